// Round 9
// baseline (267.506 us; speedup 1.0000x reference)
//
#include <hip/hip_runtime.h>
#include <hip/hip_bf16.h>

#define B_ 128
#define L_ 1024
#define T_ 64

using short8 = __attribute__((ext_vector_type(8))) short;
using f32x4  = __attribute__((ext_vector_type(4))) float;
using f32x16 = __attribute__((ext_vector_type(16))) float;

static __device__ __forceinline__ unsigned short bfb(float x) {
  return __builtin_bit_cast(unsigned short, __float2bfloat16(x));
}
static __device__ __forceinline__ float asf(unsigned u) { return __builtin_bit_cast(float, u); }
static __device__ __forceinline__ float bf2f(unsigned short b) { return asf(((unsigned)b) << 16); }
// packed 2xf32 -> bf16x2 dword via RNE (verified r5)
static __device__ __forceinline__ unsigned pk2(float lo, float hi) {
  __hip_bfloat162 h = __float22bfloat162_rn(float2{lo, hi});
  unsigned u;
  __builtin_memcpy(&u, &h, 4);
  return u;
}
// packed 2xf32 -> bf16x2 dword by TRUNCATION: one v_perm_b32 (verified r8)
static __device__ __forceinline__ unsigned pk2t(float lo, float hi) {
  return __builtin_amdgcn_perm(__builtin_bit_cast(unsigned, hi),
                               __builtin_bit_cast(unsigned, lo), 0x07060302u);
}
// gfx950 half-wave exchange: x' = {x.lo, y.lo}, y' = {x.hi, y.hi} (verified r5)
static __device__ __forceinline__ void pswap(unsigned& x, unsigned& y) {
  asm("v_permlane32_swap_b32 %0, %1" : "+v"(x), "+v"(y));
}

// ---------- K0: expET[i][k] = exp(trans[k][i])  (bf16, A-operand table) ----------
__global__ __launch_bounds__(256) void k_prep(const float* __restrict__ trans,
                                              unsigned short* __restrict__ expET) {
  int t = blockIdx.x * 256 + threadIdx.x;  // 4096
  expET[t] = bfb(__expf(trans[(t & 63) * T_ + (t >> 6)]));
}

// ---------- K1: F[token][tag] = softmax_tag(embed[x]·W + b)  (bf16) ----------
// W staged via LDS with the r2-verified B-frag swizzle (coalesced fp32 global reads,
// then 32x ds_read_b128 per lane) instead of 256 scattered scalar global loads.
__global__ __launch_bounds__(256) void k_emis(const int* __restrict__ x,
                                              const float* __restrict__ embed,
                                              const float* __restrict__ W,
                                              const float* __restrict__ bias,
                                              unsigned short* __restrict__ Fout) {
  __shared__ unsigned short Wsw[16384];  // 32 KB
  for (int e = threadIdx.x; e < 16384; e += 256) {
    int k = e >> 6, n = e & 63;  // W[k][n]
    int idx = ((k >> 5) << 11) + ((n >> 4) << 9) + (((k >> 3) & 3) << 7) + ((n & 15) << 3) + (k & 7);
    Wsw[idx] = bfb(W[e]);
  }
  __syncthreads();
  const int L = threadIdx.x & 63, wv = threadIdx.x >> 6, m = L & 15, q = L >> 4;
  short8 Wf[8][4];
#pragma unroll
  for (int kk = 0; kk < 8; kk++)
#pragma unroll
    for (int u = 0; u < 4; u++)
      Wf[kk][u] = *(const short8*)&Wsw[kk * 2048 + u * 512 + q * 128 + m * 8];
  const float bj0 = bias[m], bj1 = bias[16 + m], bj2 = bias[32 + m], bj3 = bias[48 + m];
  for (int it = 0; it < 4; it++) {
    const int tokbase = ((blockIdx.x * 4 + wv) * 4 + it) * 16;
    const float* er = embed + (size_t)x[tokbase + m] * 256;
    f32x4 acc[4] = {{0.f,0.f,0.f,0.f},{0.f,0.f,0.f,0.f},{0.f,0.f,0.f,0.f},{0.f,0.f,0.f,0.f}};
#pragma unroll
    for (int kap = 0; kap < 8; kap++) {
      float4 p0 = *(const float4*)(er + 32 * kap + 8 * q);
      float4 p1 = *(const float4*)(er + 32 * kap + 8 * q + 4);
      unsigned u0 = pk2(p0.x, p0.y), u1 = pk2(p0.z, p0.w);
      unsigned u2 = pk2(p1.x, p1.y), u3 = pk2(p1.z, p1.w);
      short8 af = __builtin_bit_cast(short8, make_uint4(u0, u1, u2, u3));
#pragma unroll
      for (int u = 0; u < 4; u++)
        acc[u] = __builtin_amdgcn_mfma_f32_16x16x32_bf16(af, Wf[kap][u], acc[u], 0, 0, 0);
    }
    // D: row(token) = 4q+r, col(tag) = 16u+m. Softmax over tags.
#pragma unroll
    for (int r = 0; r < 4; r++) {
      float e0 = acc[0][r] + bj0, e1 = acc[1][r] + bj1;
      float e2 = acc[2][r] + bj2, e3 = acc[3][r] + bj3;
      float mr = fmaxf(fmaxf(e0, e1), fmaxf(e2, e3));
#pragma unroll
      for (int off = 1; off < 16; off <<= 1) mr = fmaxf(mr, __shfl_xor(mr, off));
      float x0 = __expf(e0 - mr), x1 = __expf(e1 - mr);
      float x2 = __expf(e2 - mr), x3 = __expf(e3 - mr);
      float sr = (x0 + x1) + (x2 + x3);
#pragma unroll
      for (int off = 1; off < 16; off <<= 1) sr += __shfl_xor(sr, off);
      float rs = 1.0f / sr;
      unsigned short* Fp = Fout + (size_t)(tokbase + 4 * q + r) * T_ + m;
      Fp[0]  = bfb(x0 * rs);
      Fp[16] = bfb(x1 * rs);
      Fp[32] = bfb(x2 * rs);
      Fp[48] = bfb(x3 * rs);
    }
  }
}

// ---------- K2 phase 1: chunk transfer matrices  X_c = prod_{l in chunk} (diag(F_l)·E^T) ----
// One wave per (batch, chunk). J-split: 32 output columns at a time (halves live acc regs).
// Renorm kept (every 16 steps); scale factor taken from the J=0 half's max — a wave-uniform
// approximate max is sufficient (renorm is precision-scale management; log exactly tracked).
__global__ __launch_bounds__(64) void k_scan(const unsigned short* __restrict__ F,
                                             const unsigned short* __restrict__ expET,
                                             unsigned short* __restrict__ XT,
                                             float* __restrict__ rlog,
                                             int Cshift) {
  const int job = blockIdx.x;
  const int C = 1 << Cshift;
  const int c = job & (C - 1);
  const int b = job >> Cshift;
  const int K = (1023 + C - 1) >> Cshift;
  const int a = 1 + c * K;
  const int len = min(K, 1024 - a);
  const int L = threadIdx.x, nh = L & 31, hh = L >> 5;

  // A = E^T static frags: A[m=lane&31][k=16*kap+8*hh+d]
  short8 Af[2][4];
#pragma unroll
  for (int I = 0; I < 2; I++)
#pragma unroll
    for (int kap = 0; kap < 4; kap++)
      Af[I][kap] = *(const short8*)(expET + (32 * I + nh) * T_ + 16 * kap + 8 * hh);

  // B = X = Identity (bf16)
  unsigned Bf[4][2][4];
#pragma unroll
  for (int kap = 0; kap < 4; kap++)
#pragma unroll
    for (int J = 0; J < 2; J++)
#pragma unroll
      for (int dw = 0; dw < 4; dw++) {
        int k0 = 16 * kap + 8 * hh + 2 * dw, n = 32 * J + nh;
        unsigned u = 0;
        if (k0 == n) u = 0x3F80u;
        if (k0 + 1 == n) u = 0x3F800000u;
        Bf[kap][J][dw] = u;
      }

  const unsigned short* Fb = F + (size_t)b * (L_ * T_);
  uint2 Fc[2][4];
#pragma unroll
  for (int I = 0; I < 2; I++)
#pragma unroll
    for (int j = 0; j < 4; j++)
      Fc[I][j] = *(const uint2*)(Fb + (size_t)a * T_ + (16 * I + 4 * j + 2 * hh) * 2);

  float logacc = 0.f;
  const f32x16 Z = {};  // loop-invariant zero C operand (verified r8)

  for (int s = 0; s < len; s++) {
    // prefetch next step's F row (last iter reads one row past chunk: in-ws, unused)
    uint2 Fn[2][4];
    {
      const unsigned short* Frow = Fb + (size_t)(a + s + 1) * T_;
#pragma unroll
      for (int I = 0; I < 2; I++)
#pragma unroll
        for (int j = 0; j < 4; j++)
          Fn[I][j] = *(const uint2*)(Frow + (16 * I + 4 * j + 2 * hh) * 2);
    }
    const bool rn = ((s & 15) == 15);
    float rs = 1.0f;
#pragma unroll
    for (int J = 0; J < 2; J++) {
      // D = E^T * X for column group J (8 MFMAs)
      f32x16 D[2];
#pragma unroll
      for (int I = 0; I < 2; I++) {
        short8 b0 = __builtin_bit_cast(short8,
            make_uint4(Bf[0][J][0], Bf[0][J][1], Bf[0][J][2], Bf[0][J][3]));
        f32x16 d = __builtin_amdgcn_mfma_f32_32x32x16_bf16(Af[I][0], b0, Z, 0, 0, 0);
#pragma unroll
        for (int kap = 1; kap < 4; kap++) {
          short8 bk = __builtin_bit_cast(short8,
              make_uint4(Bf[kap][J][0], Bf[kap][J][1], Bf[kap][J][2], Bf[kap][J][3]));
          d = __builtin_amdgcn_mfma_f32_32x32x16_bf16(Af[I][kap], bk, d, 0, 0, 0);
        }
        D[I] = d;
      }
      // scale rows (row = 32I + 8j + 4hh + r) by F_l
#pragma unroll
      for (int I = 0; I < 2; I++)
#pragma unroll
        for (int j = 0; j < 4; j++) {
          uint2 g = Fc[I][j];
          float f0 = asf(g.x << 16), f1 = asf(g.x & 0xffff0000u);
          float f2 = asf(g.y << 16), f3 = asf(g.y & 0xffff0000u);
          D[I][4 * j + 0] *= f0;
          D[I][4 * j + 1] *= f1;
          D[I][4 * j + 2] *= f2;
          D[I][4 * j + 3] *= f3;
        }
      // periodic renorm: uniform scale from J=0 half's max (applied to both halves)
      if (rn) {
        if (J == 0) {
          float mx = D[0][0];
#pragma unroll
          for (int I = 0; I < 2; I++)
#pragma unroll
            for (int r = 0; r < 16; r++) mx = fmaxf(mx, D[I][r]);
#pragma unroll
          for (int off = 1; off < 64; off <<= 1) mx = fmaxf(mx, __shfl_xor(mx, off));
          rs = 1.0f / mx;
          logacc += __logf(mx);
        }
#pragma unroll
        for (int I = 0; I < 2; I++)
#pragma unroll
          for (int r = 0; r < 16; r++) D[I][r] *= rs;
      }
      // pack fp32 -> bf16 dwords by truncation
      unsigned PDt[2][4][2];
#pragma unroll
      for (int I = 0; I < 2; I++)
#pragma unroll
        for (int j = 0; j < 4; j++) {
          PDt[I][j][0] = pk2t(D[I][4 * j + 0], D[I][4 * j + 1]);
          PDt[I][j][1] = pk2t(D[I][4 * j + 2], D[I][4 * j + 3]);
        }
      if (s == len - 1) {
        // final store: X_c transposed (XT[col][rowpair]) for coalesced phase-2 reads
        unsigned* X2 = (unsigned*)(XT + (size_t)job * 4096) + (32 * J + nh) * 32;
#pragma unroll
        for (int I = 0; I < 2; I++)
#pragma unroll
          for (int j = 0; j < 4; j++) {
            X2[16 * I + 4 * j + 2 * hh + 0] = PDt[I][j][0];
            X2[16 * I + 4 * j + 2 * hh + 1] = PDt[I][j][1];
          }
      } else {
        // half-wave exchange: D 4-row groups -> B 8-row groups (verified r5)
#pragma unroll
        for (int kap = 0; kap < 4; kap++) {
          const int Ip = kap >> 1, e2 = 2 * (kap & 1);
          unsigned x0 = PDt[Ip][e2][0], y0 = PDt[Ip][e2 + 1][0];
          unsigned x1 = PDt[Ip][e2][1], y1 = PDt[Ip][e2 + 1][1];
          pswap(x0, y0);
          pswap(x1, y1);
          Bf[kap][J][0] = x0;
          Bf[kap][J][1] = x1;
          Bf[kap][J][2] = y0;
          Bf[kap][J][3] = y1;
        }
      }
    }
#pragma unroll
    for (int I = 0; I < 2; I++)
#pragma unroll
      for (int j = 0; j < 4; j++) Fc[I][j] = Fn[I][j];
  }
  if (L == 0) rlog[job] = logacc;
}

// ---------- K3 phase 2: sequential chunk application, one wave per batch ----------
__global__ __launch_bounds__(64) void k_apply(const unsigned short* __restrict__ XT,
                                              const float* __restrict__ rlog,
                                              const unsigned short* __restrict__ F,
                                              const float* __restrict__ trans,
                                              float* __restrict__ logz, int Cshift) {
  const int b = blockIdx.x, i = threadIdx.x;
  const int C = 1 << Cshift;
  __shared__ float vS[64];
  float v = __expf(trans[i]) * bf2f(F[(size_t)b * (L_ * T_) + i]);  // x0 = expT[S]*F0
  float lacc = 0.f;
  vS[i] = v;
  __syncthreads();
  for (int c = 0; c < C; c++) {
    const unsigned short* Xc = XT + (size_t)(b * C + c) * 4096;
    float a0 = 0.f, a1 = 0.f, a2 = 0.f, a3 = 0.f;
#pragma unroll
    for (int j = 0; j < 64; j += 4) {
      a0 = fmaf(bf2f(Xc[(j + 0) * T_ + i]), vS[j + 0], a0);
      a1 = fmaf(bf2f(Xc[(j + 1) * T_ + i]), vS[j + 1], a1);
      a2 = fmaf(bf2f(Xc[(j + 2) * T_ + i]), vS[j + 2], a2);
      a3 = fmaf(bf2f(Xc[(j + 3) * T_ + i]), vS[j + 3], a3);
    }
    float nv = (a0 + a1) + (a2 + a3);
    float mx = nv;
#pragma unroll
    for (int off = 1; off < 64; off <<= 1) mx = fmaxf(mx, __shfl_xor(mx, off));
    v = nv * (1.0f / mx);
    lacc += __logf(mx) + rlog[b * C + c];
    __syncthreads();
    vS[i] = v;
    __syncthreads();
  }
  float t = v * __expf(trans[i * T_ + 1]);
#pragma unroll
  for (int off = 1; off < 64; off <<= 1) t += __shfl_xor(t, off);
  if (i == 0) logz[b] = lacc + __logf(t);
}

// ---------- K4: gold path score (emission = log F + const, const cancels) ----------
__global__ __launch_bounds__(256) void k_scores(const int* __restrict__ tags,
                                                const unsigned short* __restrict__ F,
                                                const float* __restrict__ trans,
                                                float* __restrict__ score) {
  const int b = blockIdx.x;
  const int* tg = tags + (size_t)b * L_;
  const unsigned short* Fu = F + (size_t)b * (L_ * T_);
  float acc = 0.f;
  for (int l = threadIdx.x; l < L_; l += 256) {
    const int t = tg[l];
    acc += __logf(bf2f(Fu[(size_t)l * T_ + t]));
    if (l < L_ - 1) acc += trans[t * T_ + tg[l + 1]];
  }
#pragma unroll
  for (int off = 32; off > 0; off >>= 1) acc += __shfl_xor(acc, off);
  __shared__ float red[4];
  if ((threadIdx.x & 63) == 0) red[threadIdx.x >> 6] = acc;
  __syncthreads();
  if (threadIdx.x == 0) {
    float s = red[0] + red[1] + red[2] + red[3];
    s += trans[0 * T_ + tg[0]];
    s += trans[tg[L_ - 1] * T_ + 1];
    score[b] = s;
  }
}

// ---------- K5: out = -sum_b (score_b - logz_b) ----------
__global__ __launch_bounds__(128) void k_final(const float* __restrict__ score,
                                               const float* __restrict__ logz,
                                               float* __restrict__ out) {
  const int t = threadIdx.x;
  float v = score[t] - logz[t];
#pragma unroll
  for (int off = 32; off > 0; off >>= 1) v += __shfl_xor(v, off);
  __shared__ float r[2];
  if ((t & 63) == 0) r[t >> 6] = v;
  __syncthreads();
  if (t == 0) out[0] = -(r[0] + r[1]);
}

extern "C" void kernel_launch(void* const* d_in, const int* in_sizes, int n_in,
                              void* d_out, int out_size, void* d_ws, size_t ws_size,
                              hipStream_t stream) {
  const int* x = (const int*)d_in[0];
  const int* tags = (const int*)d_in[1];
  const float* embed = (const float*)d_in[3];
  const float* W = (const float*)d_in[4];
  const float* bias = (const float*)d_in[5];
  const float* trans = (const float*)d_in[6];

  const size_t fbytes = (size_t)B_ * L_ * T_ * 2;  // 16 MB
  int Cshift = 6;  // try C=64 (more waves); falls back if ws too small
  while (Cshift > 0) {
    size_t need = fbytes + (((size_t)1 << Cshift) * 1048576)   // XT
                  + (((size_t)128 << Cshift) * 4)              // rlog
                  + 1024 + 8192;                               // logz+score, expET
    if (need <= ws_size) break;
    Cshift--;
  }
  const int C = 1 << Cshift;

  char* ws = (char*)d_ws;
  unsigned short* F = (unsigned short*)ws;
  unsigned short* XT = (unsigned short*)(ws + fbytes);
  float* rlog = (float*)(ws + fbytes + (size_t)C * 1048576);
  float* logz = (float*)((char*)rlog + (size_t)128 * C * 4);
  float* score = logz + B_;
  unsigned short* expET = (unsigned short*)((char*)logz + 1024);
  float* out = (float*)d_out;

  k_prep<<<16, 256, 0, stream>>>(trans, expET);
  k_emis<<<512, 256, 0, stream>>>(x, embed, W, bias, F);
  k_scan<<<128 * C, 64, 0, stream>>>(F, expET, XT, rlog, Cshift);
  k_apply<<<B_, 64, 0, stream>>>(XT, rlog, F, trans, logz, Cshift);
  k_scores<<<B_, 256, 0, stream>>>(tags, F, trans, score);
  k_final<<<1, 128, 0, stream>>>(score, logz, out);
}

// Round 10
// 223.591 us; speedup vs baseline: 1.1964x; 1.1964x over previous
//
#include <hip/hip_runtime.h>
#include <hip/hip_bf16.h>

#define B_ 128
#define L_ 1024
#define T_ 64

using short8 = __attribute__((ext_vector_type(8))) short;
using f32x4  = __attribute__((ext_vector_type(4))) float;
using f32x16 = __attribute__((ext_vector_type(16))) float;

static __device__ __forceinline__ unsigned short bfb(float x) {
  return __builtin_bit_cast(unsigned short, __float2bfloat16(x));
}
static __device__ __forceinline__ float asf(unsigned u) { return __builtin_bit_cast(float, u); }
static __device__ __forceinline__ float bf2f(unsigned short b) { return asf(((unsigned)b) << 16); }
// packed 2xf32 -> bf16x2 dword via RNE (verified r5)
static __device__ __forceinline__ unsigned pk2(float lo, float hi) {
  __hip_bfloat162 h = __float22bfloat162_rn(float2{lo, hi});
  unsigned u;
  __builtin_memcpy(&u, &h, 4);
  return u;
}
// packed 2xf32 -> bf16x2 dword by TRUNCATION: one v_perm_b32 (verified r8)
static __device__ __forceinline__ unsigned pk2t(float lo, float hi) {
  return __builtin_amdgcn_perm(__builtin_bit_cast(unsigned, hi),
                               __builtin_bit_cast(unsigned, lo), 0x07060302u);
}
// gfx950 half-wave exchange: x' = {x.lo, y.lo}, y' = {x.hi, y.hi} (verified r5)
static __device__ __forceinline__ void pswap(unsigned& x, unsigned& y) {
  asm("v_permlane32_swap_b32 %0, %1" : "+v"(x), "+v"(y));
}

// ---------- K0: expET[i][k] = exp(trans[k][i])  (bf16, A-operand table) ----------
__global__ __launch_bounds__(256) void k_prep(const float* __restrict__ trans,
                                              unsigned short* __restrict__ expET) {
  int t = blockIdx.x * 256 + threadIdx.x;  // 4096
  expET[t] = bfb(__expf(trans[(t & 63) * T_ + (t >> 6)]));
}

// ---------- K1: F[token][tag] = softmax_tag(embed[x]·W + b)  (bf16) ----------
__global__ __launch_bounds__(256) void k_emis(const int* __restrict__ x,
                                              const float* __restrict__ embed,
                                              const float* __restrict__ W,
                                              const float* __restrict__ bias,
                                              unsigned short* __restrict__ Fout) {
  __shared__ unsigned short Wsw[16384];  // 32 KB, r2-verified B-frag swizzle
  for (int e = threadIdx.x; e < 16384; e += 256) {
    int k = e >> 6, n = e & 63;  // W[k][n]
    int idx = ((k >> 5) << 11) + ((n >> 4) << 9) + (((k >> 3) & 3) << 7) + ((n & 15) << 3) + (k & 7);
    Wsw[idx] = bfb(W[e]);
  }
  __syncthreads();
  const int L = threadIdx.x & 63, wv = threadIdx.x >> 6, m = L & 15, q = L >> 4;
  short8 Wf[8][4];
#pragma unroll
  for (int kk = 0; kk < 8; kk++)
#pragma unroll
    for (int u = 0; u < 4; u++)
      Wf[kk][u] = *(const short8*)&Wsw[kk * 2048 + u * 512 + q * 128 + m * 8];
  const float bj0 = bias[m], bj1 = bias[16 + m], bj2 = bias[32 + m], bj3 = bias[48 + m];
  for (int it = 0; it < 4; it++) {
    const int tokbase = ((blockIdx.x * 4 + wv) * 4 + it) * 16;
    const float* er = embed + (size_t)x[tokbase + m] * 256;
    f32x4 acc[4] = {{0.f,0.f,0.f,0.f},{0.f,0.f,0.f,0.f},{0.f,0.f,0.f,0.f},{0.f,0.f,0.f,0.f}};
#pragma unroll
    for (int kap = 0; kap < 8; kap++) {
      float4 p0 = *(const float4*)(er + 32 * kap + 8 * q);
      float4 p1 = *(const float4*)(er + 32 * kap + 8 * q + 4);
      unsigned u0 = pk2(p0.x, p0.y), u1 = pk2(p0.z, p0.w);
      unsigned u2 = pk2(p1.x, p1.y), u3 = pk2(p1.z, p1.w);
      short8 af = __builtin_bit_cast(short8, make_uint4(u0, u1, u2, u3));
#pragma unroll
      for (int u = 0; u < 4; u++)
        acc[u] = __builtin_amdgcn_mfma_f32_16x16x32_bf16(af, Wf[kap][u], acc[u], 0, 0, 0);
    }
    // D: row(token) = 4q+r, col(tag) = 16u+m. Softmax over tags.
#pragma unroll
    for (int r = 0; r < 4; r++) {
      float e0 = acc[0][r] + bj0, e1 = acc[1][r] + bj1;
      float e2 = acc[2][r] + bj2, e3 = acc[3][r] + bj3;
      float mr = fmaxf(fmaxf(e0, e1), fmaxf(e2, e3));
#pragma unroll
      for (int off = 1; off < 16; off <<= 1) mr = fmaxf(mr, __shfl_xor(mr, off));
      float x0 = __expf(e0 - mr), x1 = __expf(e1 - mr);
      float x2 = __expf(e2 - mr), x3 = __expf(e3 - mr);
      float sr = (x0 + x1) + (x2 + x3);
#pragma unroll
      for (int off = 1; off < 16; off <<= 1) sr += __shfl_xor(sr, off);
      float rs = 1.0f / sr;
      unsigned short* Fp = Fout + (size_t)(tokbase + 4 * q + r) * T_ + m;
      Fp[0]  = bfb(x0 * rs);
      Fp[16] = bfb(x1 * rs);
      Fp[32] = bfb(x2 * rs);
      Fp[48] = bfb(x3 * rs);
    }
  }
}

// ---------- K2 phase 1: chunk transfer matrices  X_c = prod_{l in chunk} (diag(F_l)·E^T) ----
// Loop identical to r9 (verified). Only the FINAL STORE changed: row-major XT[row*64+col]
// so k_apply's lane i reads row i as 8 contiguous uint4.
__global__ __launch_bounds__(64) void k_scan(const unsigned short* __restrict__ F,
                                             const unsigned short* __restrict__ expET,
                                             unsigned short* __restrict__ XT,
                                             float* __restrict__ rlog,
                                             int Cshift) {
  const int job = blockIdx.x;
  const int C = 1 << Cshift;
  const int c = job & (C - 1);
  const int b = job >> Cshift;
  const int K = (1023 + C - 1) >> Cshift;
  const int a = 1 + c * K;
  const int len = min(K, 1024 - a);
  const int L = threadIdx.x, nh = L & 31, hh = L >> 5;

  short8 Af[2][4];
#pragma unroll
  for (int I = 0; I < 2; I++)
#pragma unroll
    for (int kap = 0; kap < 4; kap++)
      Af[I][kap] = *(const short8*)(expET + (32 * I + nh) * T_ + 16 * kap + 8 * hh);

  unsigned Bf[4][2][4];
#pragma unroll
  for (int kap = 0; kap < 4; kap++)
#pragma unroll
    for (int J = 0; J < 2; J++)
#pragma unroll
      for (int dw = 0; dw < 4; dw++) {
        int k0 = 16 * kap + 8 * hh + 2 * dw, n = 32 * J + nh;
        unsigned u = 0;
        if (k0 == n) u = 0x3F80u;
        if (k0 + 1 == n) u = 0x3F800000u;
        Bf[kap][J][dw] = u;
      }

  const unsigned short* Fb = F + (size_t)b * (L_ * T_);
  uint2 Fc[2][4];
#pragma unroll
  for (int I = 0; I < 2; I++)
#pragma unroll
    for (int j = 0; j < 4; j++)
      Fc[I][j] = *(const uint2*)(Fb + (size_t)a * T_ + (16 * I + 4 * j + 2 * hh) * 2);

  float logacc = 0.f;
  const f32x16 Z = {};

  for (int s = 0; s < len; s++) {
    uint2 Fn[2][4];
    {
      const unsigned short* Frow = Fb + (size_t)(a + s + 1) * T_;
#pragma unroll
      for (int I = 0; I < 2; I++)
#pragma unroll
        for (int j = 0; j < 4; j++)
          Fn[I][j] = *(const uint2*)(Frow + (16 * I + 4 * j + 2 * hh) * 2);
    }
    const bool rn = ((s & 15) == 15);
    float rs = 1.0f;
#pragma unroll
    for (int J = 0; J < 2; J++) {
      f32x16 D[2];
#pragma unroll
      for (int I = 0; I < 2; I++) {
        short8 b0 = __builtin_bit_cast(short8,
            make_uint4(Bf[0][J][0], Bf[0][J][1], Bf[0][J][2], Bf[0][J][3]));
        f32x16 d = __builtin_amdgcn_mfma_f32_32x32x16_bf16(Af[I][0], b0, Z, 0, 0, 0);
#pragma unroll
        for (int kap = 1; kap < 4; kap++) {
          short8 bk = __builtin_bit_cast(short8,
              make_uint4(Bf[kap][J][0], Bf[kap][J][1], Bf[kap][J][2], Bf[kap][J][3]));
          d = __builtin_amdgcn_mfma_f32_32x32x16_bf16(Af[I][kap], bk, d, 0, 0, 0);
        }
        D[I] = d;
      }
#pragma unroll
      for (int I = 0; I < 2; I++)
#pragma unroll
        for (int j = 0; j < 4; j++) {
          uint2 g = Fc[I][j];
          float f0 = asf(g.x << 16), f1 = asf(g.x & 0xffff0000u);
          float f2 = asf(g.y << 16), f3 = asf(g.y & 0xffff0000u);
          D[I][4 * j + 0] *= f0;
          D[I][4 * j + 1] *= f1;
          D[I][4 * j + 2] *= f2;
          D[I][4 * j + 3] *= f3;
        }
      if (rn) {
        if (J == 0) {
          float mx = D[0][0];
#pragma unroll
          for (int I = 0; I < 2; I++)
#pragma unroll
            for (int r = 0; r < 16; r++) mx = fmaxf(mx, D[I][r]);
#pragma unroll
          for (int off = 1; off < 64; off <<= 1) mx = fmaxf(mx, __shfl_xor(mx, off));
          rs = 1.0f / mx;
          logacc += __logf(mx);
        }
#pragma unroll
        for (int I = 0; I < 2; I++)
#pragma unroll
          for (int r = 0; r < 16; r++) D[I][r] *= rs;
      }
      unsigned PDt[2][4][2];
#pragma unroll
      for (int I = 0; I < 2; I++)
#pragma unroll
        for (int j = 0; j < 4; j++) {
          PDt[I][j][0] = pk2t(D[I][4 * j + 0], D[I][4 * j + 1]);
          PDt[I][j][1] = pk2t(D[I][4 * j + 2], D[I][4 * j + 3]);
        }
      if (s == len - 1) {
        // ROW-MAJOR final store: XT[row*64 + col], col = 32J+nh
        unsigned short* Xrow = XT + (size_t)job * 4096 + 32 * J + nh;
#pragma unroll
        for (int I = 0; I < 2; I++)
#pragma unroll
          for (int j = 0; j < 4; j++)
#pragma unroll
            for (int p = 0; p < 2; p++) {
              const int r = 32 * I + 8 * j + 4 * hh + 2 * p;
              Xrow[(size_t)r * 64] = (unsigned short)(PDt[I][j][p] & 0xffffu);
              Xrow[(size_t)(r + 1) * 64] = (unsigned short)(PDt[I][j][p] >> 16);
            }
      } else {
#pragma unroll
        for (int kap = 0; kap < 4; kap++) {
          const int Ip = kap >> 1, e2 = 2 * (kap & 1);
          unsigned x0 = PDt[Ip][e2][0], y0 = PDt[Ip][e2 + 1][0];
          unsigned x1 = PDt[Ip][e2][1], y1 = PDt[Ip][e2 + 1][1];
          pswap(x0, y0);
          pswap(x1, y1);
          Bf[kap][J][0] = x0;
          Bf[kap][J][1] = x1;
          Bf[kap][J][2] = y0;
          Bf[kap][J][3] = y1;
        }
      }
    }
#pragma unroll
    for (int I = 0; I < 2; I++)
#pragma unroll
      for (int j = 0; j < 4; j++) Fc[I][j] = Fn[I][j];
  }
  if (L == 0) rlog[job] = logacc;
}

// ---------- K3: fused gold-score (256 thr) + chunk application (wave 0, register
//             double-buffer prefetch) + final atomicAdd into zeroed d_out ----------
__global__ __launch_bounds__(256) void k_apply(const unsigned short* __restrict__ XT,
                                               const float* __restrict__ rlog,
                                               const unsigned short* __restrict__ F,
                                               const float* __restrict__ trans,
                                               const int* __restrict__ tags,
                                               float* __restrict__ out, int Cshift) {
  const int b = blockIdx.x, tid = threadIdx.x;
  const int C = 1 << Cshift;
  __shared__ float sred[4];
  __shared__ __align__(16) float vS[64];
  const int* tg = tags + (size_t)b * L_;
  const unsigned short* Fu = F + (size_t)b * (L_ * T_);
  // gold path score (emission = log F + per-token const; const cancels against logZ)
  float acc = 0.f;
  for (int l = tid; l < L_; l += 256) {
    const int t = tg[l];
    acc += __logf(bf2f(Fu[(size_t)l * T_ + t]));
    if (l < L_ - 1) acc += trans[t * T_ + tg[l + 1]];
  }
#pragma unroll
  for (int off = 32; off > 0; off >>= 1) acc += __shfl_xor(acc, off);
  if ((tid & 63) == 0) sred[tid >> 6] = acc;
  __syncthreads();
  if (tid >= 64) return;  // waves 1..3 exit; wave 0 continues (no further barriers)
  const int i = tid;
  float score = (sred[0] + sred[1]) + (sred[2] + sred[3]);
  score += trans[tg[0]] + trans[tg[L_ - 1] * T_ + 1];
  float v = __expf(trans[i]) * bf2f(Fu[i]);  // x0 = exp(trans[START][i]) * F0[i]
  float lacc = 0.f;
  vS[i] = v;  // same-wave LDS, in-order: no barrier needed
  const uint4* Xb = (const uint4*)XT + (size_t)b * C * 512;  // 512 uint4 per chunk
  uint4 Xr[8];
#pragma unroll
  for (int t = 0; t < 8; t++) Xr[t] = Xb[i * 8 + t];  // chunk 0, row i
  for (int c = 0; c < C; c++) {
    uint4 Xn[8];
    if (c + 1 < C) {  // prefetch next chunk's row while computing this one
#pragma unroll
      for (int t = 0; t < 8; t++) Xn[t] = Xb[(size_t)(c + 1) * 512 + i * 8 + t];
    }
    float nv = 0.f;
#pragma unroll
    for (int t = 0; t < 8; t++) {  // uint4 t covers cols 8t..8t+7
      float4 va = *(const float4*)&vS[8 * t];
      float4 vb = *(const float4*)&vS[8 * t + 4];
      nv = fmaf(asf(Xr[t].x << 16), va.x, nv);
      nv = fmaf(asf(Xr[t].x & 0xffff0000u), va.y, nv);
      nv = fmaf(asf(Xr[t].y << 16), va.z, nv);
      nv = fmaf(asf(Xr[t].y & 0xffff0000u), va.w, nv);
      nv = fmaf(asf(Xr[t].z << 16), vb.x, nv);
      nv = fmaf(asf(Xr[t].z & 0xffff0000u), vb.y, nv);
      nv = fmaf(asf(Xr[t].w << 16), vb.z, nv);
      nv = fmaf(asf(Xr[t].w & 0xffff0000u), vb.w, nv);
    }
    float mx = nv;
#pragma unroll
    for (int off = 1; off < 64; off <<= 1) mx = fmaxf(mx, __shfl_xor(mx, off));
    v = nv * (1.0f / mx);
    lacc += __logf(mx) + rlog[b * C + c];
    vS[i] = v;
#pragma unroll
    for (int t = 0; t < 8; t++) Xr[t] = Xn[t];
  }
  float t2 = v * __expf(trans[i * T_ + 1]);
#pragma unroll
  for (int off = 1; off < 64; off <<= 1) t2 += __shfl_xor(t2, off);
  if (i == 0) {
    const float logz = lacc + __logf(t2);
    atomicAdd(out, -(score - logz));
  }
}

extern "C" void kernel_launch(void* const* d_in, const int* in_sizes, int n_in,
                              void* d_out, int out_size, void* d_ws, size_t ws_size,
                              hipStream_t stream) {
  const int* x = (const int*)d_in[0];
  const int* tags = (const int*)d_in[1];
  const float* embed = (const float*)d_in[3];
  const float* W = (const float*)d_in[4];
  const float* bias = (const float*)d_in[5];
  const float* trans = (const float*)d_in[6];

  const size_t fbytes = (size_t)B_ * L_ * T_ * 2;  // 16 MB
  int Cshift = 5;  // C=32: r9 showed C=64 only inflates k_apply
  while (Cshift > 0) {
    size_t need = fbytes + (((size_t)1 << Cshift) * 1048576)   // XT
                  + (((size_t)128 << Cshift) * 4)              // rlog
                  + 8192;                                      // expET
    if (need <= ws_size) break;
    Cshift--;
  }
  const int C = 1 << Cshift;

  char* ws = (char*)d_ws;
  unsigned short* F = (unsigned short*)ws;
  unsigned short* XT = (unsigned short*)(ws + fbytes);
  float* rlog = (float*)(ws + fbytes + (size_t)C * 1048576);
  unsigned short* expET = (unsigned short*)((char*)rlog + (size_t)128 * C * 4);
  float* out = (float*)d_out;

  hipMemsetAsync(out, 0, sizeof(float), stream);
  k_prep<<<16, 256, 0, stream>>>(trans, expET);
  k_emis<<<512, 256, 0, stream>>>(x, embed, W, bias, F);
  k_scan<<<128 * C, 64, 0, stream>>>(F, expET, XT, rlog, Cshift);
  k_apply<<<B_, 256, 0, stream>>>(XT, rlog, F, trans, tags, out, Cshift);
}

// Round 11
// 210.117 us; speedup vs baseline: 1.2731x; 1.0641x over previous
//
#include <hip/hip_runtime.h>
#include <hip/hip_bf16.h>

#define B_ 128
#define L_ 1024
#define T_ 64
#define CSH 5
#define C_ 32

using short8 = __attribute__((ext_vector_type(8))) short;
using f32x4  = __attribute__((ext_vector_type(4))) float;
using f32x16 = __attribute__((ext_vector_type(16))) float;

static __device__ __forceinline__ unsigned short bfb(float x) {
  return __builtin_bit_cast(unsigned short, __float2bfloat16(x));
}
static __device__ __forceinline__ float asf(unsigned u) { return __builtin_bit_cast(float, u); }
static __device__ __forceinline__ float bf2f(unsigned short b) { return asf(((unsigned)b) << 16); }
// packed 2xf32 -> bf16x2 dword via RNE (verified r5)
static __device__ __forceinline__ unsigned pk2(float lo, float hi) {
  __hip_bfloat162 h = __float22bfloat162_rn(float2{lo, hi});
  unsigned u;
  __builtin_memcpy(&u, &h, 4);
  return u;
}
// packed 2xf32 -> bf16x2 dword by TRUNCATION: one v_perm_b32 (verified r8)
static __device__ __forceinline__ unsigned pk2t(float lo, float hi) {
  return __builtin_amdgcn_perm(__builtin_bit_cast(unsigned, hi),
                               __builtin_bit_cast(unsigned, lo), 0x07060302u);
}
// gfx950 half-wave exchange (verified r5)
static __device__ __forceinline__ void pswap(unsigned& x, unsigned& y) {
  asm("v_permlane32_swap_b32 %0, %1" : "+v"(x), "+v"(y));
}

// ---------- K1: fused emission + chunk transfer-matrix scan ----------
// Block = 4 waves = 4 (batch,chunk) jobs sharing one LDS W staging.
// Per wave: (a) compute F rows a..a+31 (softmax emissions, bf16) into a private
// 4KB LDS tile via MFMA; (b) write gold log-F values; (c) run the verified r10
// scan loop with Fc read from LDS.
__global__ __launch_bounds__(256) void k_scan(const int* __restrict__ x,
                                              const int* __restrict__ tags,
                                              const float* __restrict__ embed,
                                              const float* __restrict__ W,
                                              const float* __restrict__ bias,
                                              const float* __restrict__ trans,
                                              unsigned short* __restrict__ XT,
                                              float* __restrict__ rlog,
                                              float* __restrict__ goldF) {
  __shared__ unsigned short Wsw[16384];              // 32 KB, r2-verified swizzle
  __shared__ __align__(16) unsigned short Ftile[4][2048];  // 4 KB per wave
  for (int e = threadIdx.x; e < 16384; e += 256) {
    int k = e >> 6, n = e & 63;  // W[k][n]
    int idx = ((k >> 5) << 11) + ((n >> 4) << 9) + (((k >> 3) & 3) << 7) + ((n & 15) << 3) + (k & 7);
    Wsw[idx] = bfb(W[e]);
  }
  __syncthreads();

  const int wv = threadIdx.x >> 6, L = threadIdx.x & 63;
  const int job = blockIdx.x * 4 + wv;
  const int c = job & (C_ - 1);
  const int b = job >> CSH;
  const int K = (1023 + C_ - 1) >> CSH;  // 32
  const int a = 1 + c * K;
  const int len = min(K, 1024 - a);
  const int nh = L & 31, hh = L >> 5;
  const int m = L & 15, q = L >> 4;
  unsigned short* Ft = Ftile[wv];

  // ---- emission prologue: F rows a..a+31 (token clamped at 1023) ----
  const float bj0 = bias[m], bj1 = bias[16 + m], bj2 = bias[32 + m], bj3 = bias[48 + m];
  for (int p = 0; p < 2; p++) {
    int tok = a + 16 * p + m;
    if (tok > 1023) tok = 1023;
    const float* er = embed + (size_t)x[b * 1024 + tok] * 256;
    f32x4 acc[4] = {{0.f,0.f,0.f,0.f},{0.f,0.f,0.f,0.f},{0.f,0.f,0.f,0.f},{0.f,0.f,0.f,0.f}};
#pragma unroll
    for (int kap = 0; kap < 8; kap++) {
      float4 p0 = *(const float4*)(er + 32 * kap + 8 * q);
      float4 p1 = *(const float4*)(er + 32 * kap + 8 * q + 4);
      unsigned u0 = pk2(p0.x, p0.y), u1 = pk2(p0.z, p0.w);
      unsigned u2 = pk2(p1.x, p1.y), u3 = pk2(p1.z, p1.w);
      short8 af = __builtin_bit_cast(short8, make_uint4(u0, u1, u2, u3));
#pragma unroll
      for (int u = 0; u < 4; u++) {
        short8 bf8 = *(const short8*)&Wsw[kap * 2048 + u * 512 + q * 128 + m * 8];
        acc[u] = __builtin_amdgcn_mfma_f32_16x16x32_bf16(af, bf8, acc[u], 0, 0, 0);
      }
    }
    // D: row(token) = 4q+r, col(tag) = 16u+m. Softmax over tags; store to LDS tile.
#pragma unroll
    for (int r = 0; r < 4; r++) {
      float e0 = acc[0][r] + bj0, e1 = acc[1][r] + bj1;
      float e2 = acc[2][r] + bj2, e3 = acc[3][r] + bj3;
      float mr = fmaxf(fmaxf(e0, e1), fmaxf(e2, e3));
#pragma unroll
      for (int off = 1; off < 16; off <<= 1) mr = fmaxf(mr, __shfl_xor(mr, off));
      float x0 = __expf(e0 - mr), x1 = __expf(e1 - mr);
      float x2 = __expf(e2 - mr), x3 = __expf(e3 - mr);
      float sr = (x0 + x1) + (x2 + x3);
#pragma unroll
      for (int off = 1; off < 16; off <<= 1) sr += __shfl_xor(sr, off);
      float rs = 1.0f / sr;
      const int row = 16 * p + 4 * q + r;
      Ft[row * 64 + m]      = bfb(x0 * rs);
      Ft[row * 64 + 16 + m] = bfb(x1 * rs);
      Ft[row * 64 + 32 + m] = bfb(x2 * rs);
      Ft[row * 64 + 48 + m] = bfb(x3 * rs);
    }
  }
  // gold emission values for this chunk's rows (log F at gold tag)
  if (L < len) {
    const int tgv = tags[b * 1024 + a + L];
    goldF[b * 1024 + a + L] = __logf(bf2f(Ft[L * 64 + tgv]));
  }

  // ---- A = E^T frags from trans (k_prep fused; same values as r10's expET) ----
  short8 Af[2][4];
#pragma unroll
  for (int I = 0; I < 2; I++)
#pragma unroll
    for (int kap = 0; kap < 4; kap++) {
      short8 aa;
#pragma unroll
      for (int d = 0; d < 8; d++) {
        const int k = 16 * kap + 8 * hh + d;
        aa[d] = (short)bfb(__expf(trans[k * T_ + 32 * I + nh]));
      }
      Af[I][kap] = aa;
    }

  // ---- B = X = Identity ----
  unsigned Bf[4][2][4];
#pragma unroll
  for (int kap = 0; kap < 4; kap++)
#pragma unroll
    for (int J = 0; J < 2; J++)
#pragma unroll
      for (int dw = 0; dw < 4; dw++) {
        int k0 = 16 * kap + 8 * hh + 2 * dw, n = 32 * J + nh;
        unsigned u = 0;
        if (k0 == n) u = 0x3F80u;
        if (k0 + 1 == n) u = 0x3F800000u;
        Bf[kap][J][dw] = u;
      }

  float logacc = 0.f;
  const f32x16 Z = {};

  for (int s = 0; s < len; s++) {
    // F row s from LDS (identical index pattern to r10's global read)
    uint2 Fc[2][4];
#pragma unroll
    for (int I = 0; I < 2; I++)
#pragma unroll
      for (int j = 0; j < 4; j++)
        Fc[I][j] = *(const uint2*)&Ft[s * 64 + (16 * I + 4 * j + 2 * hh) * 2];
    const bool rn = ((s & 15) == 15);
    float rs = 1.0f;
#pragma unroll
    for (int J = 0; J < 2; J++) {
      f32x16 D[2];
#pragma unroll
      for (int I = 0; I < 2; I++) {
        short8 b0 = __builtin_bit_cast(short8,
            make_uint4(Bf[0][J][0], Bf[0][J][1], Bf[0][J][2], Bf[0][J][3]));
        f32x16 d = __builtin_amdgcn_mfma_f32_32x32x16_bf16(Af[I][0], b0, Z, 0, 0, 0);
#pragma unroll
        for (int kap = 1; kap < 4; kap++) {
          short8 bk = __builtin_bit_cast(short8,
              make_uint4(Bf[kap][J][0], Bf[kap][J][1], Bf[kap][J][2], Bf[kap][J][3]));
          d = __builtin_amdgcn_mfma_f32_32x32x16_bf16(Af[I][kap], bk, d, 0, 0, 0);
        }
        D[I] = d;
      }
#pragma unroll
      for (int I = 0; I < 2; I++)
#pragma unroll
        for (int j = 0; j < 4; j++) {
          uint2 g = Fc[I][j];
          float f0 = asf(g.x << 16), f1 = asf(g.x & 0xffff0000u);
          float f2 = asf(g.y << 16), f3 = asf(g.y & 0xffff0000u);
          D[I][4 * j + 0] *= f0;
          D[I][4 * j + 1] *= f1;
          D[I][4 * j + 2] *= f2;
          D[I][4 * j + 3] *= f3;
        }
      if (rn) {
        if (J == 0) {
          float mx = D[0][0];
#pragma unroll
          for (int I = 0; I < 2; I++)
#pragma unroll
            for (int r = 0; r < 16; r++) mx = fmaxf(mx, D[I][r]);
#pragma unroll
          for (int off = 1; off < 64; off <<= 1) mx = fmaxf(mx, __shfl_xor(mx, off));
          rs = 1.0f / mx;
          logacc += __logf(mx);
        }
#pragma unroll
        for (int I = 0; I < 2; I++)
#pragma unroll
          for (int r = 0; r < 16; r++) D[I][r] *= rs;
      }
      unsigned PDt[2][4][2];
#pragma unroll
      for (int I = 0; I < 2; I++)
#pragma unroll
        for (int j = 0; j < 4; j++) {
          PDt[I][j][0] = pk2t(D[I][4 * j + 0], D[I][4 * j + 1]);
          PDt[I][j][1] = pk2t(D[I][4 * j + 2], D[I][4 * j + 3]);
        }
      if (s == len - 1) {
        // row-major final store: XT[row*64 + col], col = 32J+nh (verified r10)
        unsigned short* Xrow = XT + (size_t)job * 4096 + 32 * J + nh;
#pragma unroll
        for (int I = 0; I < 2; I++)
#pragma unroll
          for (int j = 0; j < 4; j++)
#pragma unroll
            for (int pp = 0; pp < 2; pp++) {
              const int r = 32 * I + 8 * j + 4 * hh + 2 * pp;
              Xrow[(size_t)r * 64] = (unsigned short)(PDt[I][j][pp] & 0xffffu);
              Xrow[(size_t)(r + 1) * 64] = (unsigned short)(PDt[I][j][pp] >> 16);
            }
      } else {
#pragma unroll
        for (int kap = 0; kap < 4; kap++) {
          const int Ip = kap >> 1, e2 = 2 * (kap & 1);
          unsigned x0 = PDt[Ip][e2][0], y0 = PDt[Ip][e2 + 1][0];
          unsigned x1 = PDt[Ip][e2][1], y1 = PDt[Ip][e2 + 1][1];
          pswap(x0, y0);
          pswap(x1, y1);
          Bf[kap][J][0] = x0;
          Bf[kap][J][1] = x1;
          Bf[kap][J][2] = y0;
          Bf[kap][J][3] = y1;
        }
      }
    }
  }
  if (L == 0) rlog[job] = logacc;
}

// ---------- K2: gold score (256 thr, goldF + trans pairs) + row-0 emission inline
//             + sequential chunk application (wave 0) + atomicAdd into zeroed out ----
__global__ __launch_bounds__(256) void k_apply(const unsigned short* __restrict__ XT,
                                               const float* __restrict__ rlog,
                                               const float* __restrict__ goldF,
                                               const int* __restrict__ x,
                                               const float* __restrict__ embed,
                                               const float* __restrict__ W,
                                               const float* __restrict__ bias,
                                               const float* __restrict__ trans,
                                               const int* __restrict__ tags,
                                               float* __restrict__ out) {
  const int b = blockIdx.x, tid = threadIdx.x;
  __shared__ float sred[4];
  __shared__ __align__(16) float vS[64];
  const int* tg = tags + (size_t)b * L_;
  float acc = 0.f;
  for (int l = tid; l < L_; l += 256) {
    if (l > 0) acc += goldF[(size_t)b * L_ + l];
    if (l < L_ - 1) acc += trans[tg[l] * T_ + tg[l + 1]];
  }
#pragma unroll
  for (int off = 32; off > 0; off >>= 1) acc += __shfl_xor(acc, off);
  if ((tid & 63) == 0) sred[tid >> 6] = acc;
  __syncthreads();
  if (tid >= 64) return;  // wave 0 continues alone (no further barriers)
  const int i = tid;
  float score = (sred[0] + sred[1]) + (sred[2] + sred[3]);
  // row-0 emission: logits e[i] = embed[x0] . W[:,i] + b[i]
  const float* er0 = embed + (size_t)x[(size_t)b * L_] * 256;
  float e = bias[i];
#pragma unroll 8
  for (int d = 0; d < 256; d++) e = fmaf(er0[d], W[d * T_ + i], e);
  float mr = e;
#pragma unroll
  for (int off = 1; off < 64; off <<= 1) mr = fmaxf(mr, __shfl_xor(mr, off));
  float pex = __expf(e - mr);
  float sr = pex;
#pragma unroll
  for (int off = 1; off < 64; off <<= 1) sr += __shfl_xor(sr, off);
  const int t0 = tg[0];
  score += (__shfl(e, t0) - mr) - __logf(sr);          // gold l=0: log softmax
  score += trans[t0] + trans[tg[L_ - 1] * T_ + 1];     // START->t0, last->END
  float v = __expf(trans[i]) * (pex / sr);             // x0 = expT[START][i]*F0[i]
  float lacc = 0.f;
  vS[i] = v;  // same-wave LDS, in-order
  const uint4* Xb = (const uint4*)XT + (size_t)b * C_ * 512;
  uint4 Xr[8];
#pragma unroll
  for (int t = 0; t < 8; t++) Xr[t] = Xb[i * 8 + t];
  for (int c = 0; c < C_; c++) {
    uint4 Xn[8];
    if (c + 1 < C_) {
#pragma unroll
      for (int t = 0; t < 8; t++) Xn[t] = Xb[(size_t)(c + 1) * 512 + i * 8 + t];
    }
    float nv = 0.f;
#pragma unroll
    for (int t = 0; t < 8; t++) {
      float4 va = *(const float4*)&vS[8 * t];
      float4 vb = *(const float4*)&vS[8 * t + 4];
      nv = fmaf(asf(Xr[t].x << 16), va.x, nv);
      nv = fmaf(asf(Xr[t].x & 0xffff0000u), va.y, nv);
      nv = fmaf(asf(Xr[t].y << 16), va.z, nv);
      nv = fmaf(asf(Xr[t].y & 0xffff0000u), va.w, nv);
      nv = fmaf(asf(Xr[t].z << 16), vb.x, nv);
      nv = fmaf(asf(Xr[t].z & 0xffff0000u), vb.y, nv);
      nv = fmaf(asf(Xr[t].w << 16), vb.z, nv);
      nv = fmaf(asf(Xr[t].w & 0xffff0000u), vb.w, nv);
    }
    float mx = nv;
#pragma unroll
    for (int off = 1; off < 64; off <<= 1) mx = fmaxf(mx, __shfl_xor(mx, off));
    v = nv * (1.0f / mx);
    lacc += __logf(mx) + rlog[b * C_ + c];
    vS[i] = v;
#pragma unroll
    for (int t = 0; t < 8; t++) Xr[t] = Xn[t];
  }
  float t2 = v * __expf(trans[i * T_ + 1]);
#pragma unroll
  for (int off = 1; off < 64; off <<= 1) t2 += __shfl_xor(t2, off);
  if (i == 0) {
    const float logz = lacc + __logf(t2);
    atomicAdd(out, -(score - logz));
  }
}

extern "C" void kernel_launch(void* const* d_in, const int* in_sizes, int n_in,
                              void* d_out, int out_size, void* d_ws, size_t ws_size,
                              hipStream_t stream) {
  const int* x = (const int*)d_in[0];
  const int* tags = (const int*)d_in[1];
  const float* embed = (const float*)d_in[3];
  const float* W = (const float*)d_in[4];
  const float* bias = (const float*)d_in[5];
  const float* trans = (const float*)d_in[6];

  char* ws = (char*)d_ws;
  unsigned short* XT = (unsigned short*)ws;                 // 128*C jobs * 8KB = 32 MB
  float* rlog = (float*)(ws + (size_t)C_ * 1048576);        // 16 KB
  float* goldF = (float*)((char*)rlog + (size_t)128 * C_ * 4);  // 512 KB
  float* out = (float*)d_out;

  hipMemsetAsync(out, 0, sizeof(float), stream);
  k_scan<<<32 * C_, 256, 0, stream>>>(x, tags, embed, W, bias, trans, XT, rlog, goldF);
  k_apply<<<B_, 256, 0, stream>>>(XT, rlog, goldF, x, embed, W, bias, trans, tags, out);
}